// Round 5
// baseline (331.601 us; speedup 1.0000x reference)
//
#include <hip/hip_runtime.h>

// KMeans assignment: costs[i] = min_k ||x_i-c_k||^2, indices[i] = argmin_k.
// argmin over k of (c2[k] - 2*dot(x,c_k)); x2 additive, added at the end.
// Cross term via split-f16 3-pass MFMA (xh.ch + xl.ch + xh.cl), err ~1e-6.
// R10: BARRIER-FREE main loop -- B straight from L2 at point of use.
//   Cycle audit of R5/R8/R9 (all ~116-121us): MFMA 119K + LDS 74K + VALU
//   90K cyc/CU == measured duration -> pipes SERIALIZED by the per-chunk
//   barrier phase-lock (counted vmcnt didn't help because the barrier
//   itself re-locksteps the 8 waves/CU). The barrier existed only for the
//   block-shared Bh LDS dbuf; B (512KB hi+lo) is L2-resident, so load
//   bh[4]/bl[4] TRANSIENTLY from L2 in each chunk -- no LDS staging for B,
//   no prefetch arrays (R6's pinned dbuf regs spilled; transient loads
//   rotate freely), no barriers -> waves slip, pipes overlap (m114).
//   LDS = 64KB A (XOR-swizzled, proven) + 2KB reduce = 66KB, 2 blocks/CU.
// Known-bad: R6 pinned reg-dbuf (365MB scratch); R7 packed-key argmin
// (near-tie flips, idx absmax 758); R8 pass-3 hoist (-13%, mid-chunk
// drain); R9 sched_barrier pins (spill, 11.8MB writes).
// N=131072, D=128, K=1024.  d_out = [costs (N f32), indices-as-f32 (N)].

typedef _Float16 f16x8 __attribute__((ext_vector_type(8)));
typedef float    f32x4 __attribute__((ext_vector_type(4)));
typedef unsigned short u16;

constexpr int N = 131072, D = 128, K = 1024;
constexpr int MT = 128;   // points per block

union H2U { _Float16 h; unsigned short u; };

// ---- prep: centers -> hi/lo f16 in fragment-major tiled layout + exact c2 ----
// ushort idx: (((cb*4 + kc)*4 + q)*128 + c%128)*8 + j, k = kc*32 + q*8 + j
__global__ void prep_centers(const float* __restrict__ centers,
                             u16* __restrict__ Bh, u16* __restrict__ Bl,
                             float* __restrict__ c2) {
  const int wave = threadIdx.x >> 6, lane = threadIdx.x & 63;
  const int c = blockIdx.x * 4 + wave;          // one wave per center
  const float2 v = ((const float2*)(centers + (size_t)c * D))[lane];
  float s = v.x * v.x + v.y * v.y;
  #pragma unroll
  for (int off = 32; off; off >>= 1) s += __shfl_xor(s, off, 64);
  if (lane == 0) c2[c] = s;

  H2U h0, h1, l0, l1;
  h0.h = (_Float16)v.x;  l0.h = (_Float16)(v.x - (float)h0.h);
  h1.h = (_Float16)v.y;  l1.h = (_Float16)(v.y - (float)h1.h);
  const int cb = c >> 7, cm = c & 127;
  const int kc = lane >> 4, q = (lane >> 2) & 3, j0 = (lane & 3) * 2;
  const size_t off = (((size_t)(cb * 4 + kc) * 4 + q) * 128 + cm) * 8 + j0;
  *(unsigned*)(Bh + off) = (unsigned)h0.u | ((unsigned)h1.u << 16);
  *(unsigned*)(Bl + off) = (unsigned)l0.u | ((unsigned)l1.u << 16);
}

// ---- main: 128 pts x 1024 centers per block; wave tile 64x64 (2x2 waves) ----
__global__ __launch_bounds__(256, 2) void kmeans_mfma(
    const float* __restrict__ x,
    const u16* __restrict__ Bh_g, const u16* __restrict__ Bl_g,
    const float* __restrict__ c2g,
    float* __restrict__ out_cost, float* __restrict__ out_idx)
{
  // 66 KB: A [0,32768) u16 swizzled, reduce arrays [32768,33792)
  __shared__ __align__(16) u16 smem[33792];
  u16* Ah = smem;            // [g16][m128][j8] swizzled  32 KB
  u16* Al = smem + 16384;    //                           32 KB

  const int tid = threadIdx.x;
  const int wave = tid >> 6, lane = tid & 63;
  const int wr = wave >> 1, wc = wave & 1;    // wave row/col in 2x2
  const int q = lane >> 4, ln = lane & 15;
  const int m0 = blockIdx.x * MT;

  // ---- stage A tile: fp32 -> (hi,lo) f16, XOR-swizzled tiled layout ----
  #pragma unroll
  for (int i = 0; i < 16; ++i) {
    const int flat = i * 256 + tid;            // 4096 float4s = 128x128 floats
    const int m = flat >> 5, c4 = flat & 31, k0 = c4 * 4;
    const float4 v = *(const float4*)(x + (size_t)(m0 + m) * D + k0);
    const int g = k0 >> 3;                     // k-group in [0,16)
    const int j0 = k0 & 7;                     // 0 or 4
    const float vv[4] = {v.x, v.y, v.z, v.w};
    H2U h[4], l[4];
    #pragma unroll
    for (int z = 0; z < 4; ++z) {
      h[z].h = (_Float16)vv[z];
      l[z].h = (_Float16)(vv[z] - (float)h[z].h);
    }
    const int off = ((g * 128 + m) * 8 + j0) ^ ((g & 7) << 3);
    uint2 hp, lp;
    hp.x = h[0].u | ((unsigned)h[1].u << 16); hp.y = h[2].u | ((unsigned)h[3].u << 16);
    lp.x = l[0].u | ((unsigned)l[1].u << 16); lp.y = l[2].u | ((unsigned)l[3].u << 16);
    *(uint2*)(Ah + off) = hp;
    *(uint2*)(Al + off) = lp;
  }
  __syncthreads();   // A visible to all waves; LAST barrier until reduce

  // ---- x2 per point (thread tid<128 owns m=tid); A persists in LDS ----
  float x2m = 0.f;
  if (tid < MT) {
    #pragma unroll
    for (int g = 0; g < 16; ++g) {
      const int off = ((g * 128 + tid) * 8) ^ ((g & 7) << 3);
      const f16x8 hv = *(const f16x8*)(Ah + off);
      const f16x8 lv = *(const f16x8*)(Al + off);
      #pragma unroll
      for (int e = 0; e < 8; ++e) {
        const float xv = (float)hv[e] + (float)lv[e];
        x2m += xv * xv;
      }
    }
  }

  // B fragment addresses (L2-resident, fragment-major); loads are TRANSIENT
  auto bhPtr = [&](int cc, int t) {
    return (const f16x8*)(Bh_g +
        ((size_t)(cc * 4 + q) * 128 + wc * 64 + t * 16 + ln) * 8);
  };
  auto blPtr = [&](int cc, int t) {
    return (const f16x8*)(Bl_g +
        ((size_t)(cc * 4 + q) * 128 + wc * 64 + t * 16 + ln) * 8);
  };

  float bestV[16]; int bestI[16];
  #pragma unroll
  for (int b = 0; b < 16; ++b) { bestV[b] = 3.4e38f; bestI[b] = 0; }

  for (int ct = 0; ct < 8; ++ct) {
    f32x4 acc[4][4];
    #pragma unroll
    for (int mt = 0; mt < 4; ++mt)
      #pragma unroll
      for (int nt = 0; nt < 4; ++nt)
        acc[mt][nt] = (f32x4){0.f, 0.f, 0.f, 0.f};

    // c2 for this ct tile, direct from L2; hidden under the chunk compute
    float c2v[4];
    #pragma unroll
    for (int nt = 0; nt < 4; ++nt)
      c2v[nt] = c2g[ct * 128 + wc * 64 + nt * 16 + ln];

    #pragma unroll
    for (int kc = 0; kc < 4; ++kc) {
      const int cc = ct * 4 + kc;              // chunk id

      // transient B fragments straight from L2 (issue first -> latency
      // overlaps the LDS reads below; no pinning across iterations)
      f16x8 bh[4], bl[4];
      #pragma unroll
      for (int t = 0; t < 4; ++t) { bh[t] = *bhPtr(cc, t); bl[t] = *blPtr(cc, t); }

      f16x8 ah[4], al[4];
      #pragma unroll
      for (int t = 0; t < 4; ++t) {
        const int gg = kc * 4 + q;
        const int moff = ((gg * 128 + wr * 64 + t * 16 + ln) * 8) ^ ((gg & 7) << 3);
        ah[t] = *(const f16x8*)(Ah + moff);
        al[t] = *(const f16x8*)(Al + moff);
      }

      // 3-pass split-f16: 48 MFMA per chunk
      __builtin_amdgcn_s_setprio(1);
      #pragma unroll
      for (int mt = 0; mt < 4; ++mt)
        #pragma unroll
        for (int nt = 0; nt < 4; ++nt)
          acc[mt][nt] = __builtin_amdgcn_mfma_f32_16x16x32_f16(ah[mt], bh[nt], acc[mt][nt], 0, 0, 0);
      #pragma unroll
      for (int mt = 0; mt < 4; ++mt)
        #pragma unroll
        for (int nt = 0; nt < 4; ++nt)
          acc[mt][nt] = __builtin_amdgcn_mfma_f32_16x16x32_f16(al[mt], bh[nt], acc[mt][nt], 0, 0, 0);
      #pragma unroll
      for (int mt = 0; mt < 4; ++mt)
        #pragma unroll
        for (int nt = 0; nt < 4; ++nt)
          acc[mt][nt] = __builtin_amdgcn_mfma_f32_16x16x32_f16(ah[mt], bl[nt], acc[mt][nt], 0, 0, 0);
      __builtin_amdgcn_s_setprio(0);
    }

    // epilogue: s = c2 - 2*dot; running min (n strictly increasing per lane)
    #pragma unroll
    for (int nt = 0; nt < 4; ++nt) {
      const int n = ct * 128 + wc * 64 + nt * 16 + ln;
      #pragma unroll
      for (int mt = 0; mt < 4; ++mt)
        #pragma unroll
        for (int r = 0; r < 4; ++r) {
          const float s = __builtin_fmaf(-2.f, acc[mt][nt][r], c2v[nt]);
          const int b = mt * 4 + r;
          if (s < bestV[b]) { bestV[b] = s; bestI[b] = n; }
        }
    }
  }

  // ---- reduce across the 16 lanes (ln) sharing the same m rows ----
  #pragma unroll
  for (int b = 0; b < 16; ++b) {
    float v = bestV[b]; int idx = bestI[b];
    #pragma unroll
    for (int off = 1; off < 16; off <<= 1) {
      const float ov = __shfl_xor(v, off, 64);
      const int   oi = __shfl_xor(idx, off, 64);
      if (ov < v || (ov == v && oi < idx)) { v = ov; idx = oi; }
    }
    bestV[b] = v; bestI[b] = idx;
  }

  float* redV = (float*)(smem + 32768);  // 1 KB (disjoint from A)
  int*   redI = (int*)(smem + 33280);    // 1 KB
  if (ln == 0) {
    #pragma unroll
    for (int b = 0; b < 16; ++b) {
      const int ml = wr * 64 + (b >> 2) * 16 + q * 4 + (b & 3);
      redV[ml * 2 + wc] = bestV[b];
      redI[ml * 2 + wc] = bestI[b];
    }
  }
  __syncthreads();   // all waves' reduce writes visible
  if (tid < MT) {
    float v = redV[tid * 2]; int idx = redI[tid * 2];
    const float v1 = redV[tid * 2 + 1]; const int i1 = redI[tid * 2 + 1];
    if (v1 < v || (v1 == v && i1 < idx)) { v = v1; idx = i1; }
    float cost = x2m + v;
    if (cost < 0.f) cost = 0.f;          // clamp like reference
    out_cost[m0 + tid] = cost;
    out_idx[m0 + tid]  = (float)idx;
  }
}

extern "C" void kernel_launch(void* const* d_in, const int* in_sizes, int n_in,
                              void* d_out, int out_size, void* d_ws, size_t ws_size,
                              hipStream_t stream) {
  const float* x       = (const float*)d_in[0];
  const float* centers = (const float*)d_in[1];
  u16*   Bh = (u16*)d_ws;                    // 256 KB
  u16*   Bl = Bh + (size_t)K * D;            // 256 KB
  float* c2 = (float*)(Bl + (size_t)K * D);  // 4 KB
  float* out_cost = (float*)d_out;
  float* out_idx  = out_cost + N;

  prep_centers<<<K / 4, 256, 0, stream>>>(centers, Bh, Bl, c2);
  kmeans_mfma<<<N / MT, 256, 0, stream>>>(x, Bh, Bl, c2, out_cost, out_idx);
}

// Round 6
// 192.386 us; speedup vs baseline: 1.7236x; 1.7236x over previous
//
#include <hip/hip_runtime.h>

// KMeans assignment: costs[i] = min_k ||x_i-c_k||^2, indices[i] = argmin_k.
// argmin over k of (c2[k] - 2*dot(x,c_k)); x2 additive, added at the end.
// Cross term via split-f16 3-pass MFMA (xh.ch + xl.ch + xh.cl), err ~1e-6.
// R11: barrier-free main loop, RE-TILED so it cannot spill.
//   Root cause of R6/R9/R10 regressions (365/12/87 MB scratch writes): too
//   many concurrently-live B fragments -- R10's '#pragma unroll' on kc let
//   the scheduler hoist 4 chunks x 8 f16x8 = 128 VGPRs of B in flight.
//   Fix is structural: MT=64, 4 waves/block, wave tile 32x64 -> acc 64->32
//   regs, best 32->16; '#pragma unroll 1' on ct and kc bounds in-flight B
//   to ONE chunk (32 transient regs). Live set ~130 << 256 cap.
//   B (512 KB hi+lo) read straight from L2 at point of use -> NO barrier
//   in the main loop; LDS = A 32 KB + red 0.5 KB = 33 KB -> 3-4 blocks/CU
//   = 12-16 free-running waves/CU -> MFMA/LDS/VMEM pipes overlap (m114)
//   instead of the R5 barrier phase-lock (MFMA 119K + LDS 74K + VALU 90K
//   cyc/CU serialized == 116us).
//   A LDS XOR-swizzle kept (proven: conflicts 3.68M -> 8.2K).
// Known-bad: pinned/unroll-hoisted B regs (R6/R10 spill); packed-key argmin
// (R7, near-tie flips, idx absmax 758); mid-chunk barrier split (R8 -13%);
// sched_barrier(0) pins (R9 spill).
// N=131072, D=128, K=1024.  d_out = [costs (N f32), indices-as-f32 (N)].

typedef _Float16 f16x8 __attribute__((ext_vector_type(8)));
typedef float    f32x4 __attribute__((ext_vector_type(4)));
typedef unsigned short u16;

constexpr int N = 131072, D = 128, K = 1024;
constexpr int MT = 64;    // points per block (was 128)

union H2U { _Float16 h; unsigned short u; };

// ---- prep: centers -> hi/lo f16 in fragment-major tiled layout + exact c2 ----
// ushort idx: (((cb*4 + kc)*4 + q)*128 + c%128)*8 + j, k = kc*32 + q*8 + j
__global__ void prep_centers(const float* __restrict__ centers,
                             u16* __restrict__ Bh, u16* __restrict__ Bl,
                             float* __restrict__ c2) {
  const int wave = threadIdx.x >> 6, lane = threadIdx.x & 63;
  const int c = blockIdx.x * 4 + wave;          // one wave per center
  const float2 v = ((const float2*)(centers + (size_t)c * D))[lane];
  float s = v.x * v.x + v.y * v.y;
  #pragma unroll
  for (int off = 32; off; off >>= 1) s += __shfl_xor(s, off, 64);
  if (lane == 0) c2[c] = s;

  H2U h0, h1, l0, l1;
  h0.h = (_Float16)v.x;  l0.h = (_Float16)(v.x - (float)h0.h);
  h1.h = (_Float16)v.y;  l1.h = (_Float16)(v.y - (float)h1.h);
  const int cb = c >> 7, cm = c & 127;
  const int kc = lane >> 4, q = (lane >> 2) & 3, j0 = (lane & 3) * 2;
  const size_t off = (((size_t)(cb * 4 + kc) * 4 + q) * 128 + cm) * 8 + j0;
  *(unsigned*)(Bh + off) = (unsigned)h0.u | ((unsigned)h1.u << 16);
  *(unsigned*)(Bl + off) = (unsigned)l0.u | ((unsigned)l1.u << 16);
}

// ---- main: 64 pts x 1024 centers per block; wave tile 32x64 (2x2 waves) ----
__global__ __launch_bounds__(256, 2) void kmeans_mfma(
    const float* __restrict__ x,
    const u16* __restrict__ Bh_g, const u16* __restrict__ Bl_g,
    const float* __restrict__ c2g,
    float* __restrict__ out_cost, float* __restrict__ out_idx)
{
  // 33 KB: Ah [0,8192) u16, Al [8192,16384), red [16384,16896)
  __shared__ __align__(16) u16 smem[16896];
  u16* Ah = smem;            // [g16][m64][j8] swizzled  16 KB
  u16* Al = smem + 8192;     //                          16 KB

  const int tid = threadIdx.x;
  const int wave = tid >> 6, lane = tid & 63;
  const int wr = wave >> 1, wc = wave & 1;    // wave row/col in 2x2
  const int q = lane >> 4, ln = lane & 15;
  const int m0 = blockIdx.x * MT;

  // ---- stage A tile: fp32 -> (hi,lo) f16, XOR-swizzled tiled layout ----
  #pragma unroll
  for (int i = 0; i < 8; ++i) {
    const int flat = i * 256 + tid;            // 2048 float4s = 64x128 floats
    const int m = flat >> 5, c4 = flat & 31, k0 = c4 * 4;
    const float4 v = *(const float4*)(x + (size_t)(m0 + m) * D + k0);
    const int g = k0 >> 3;                     // k-group in [0,16)
    const int j0 = k0 & 7;                     // 0 or 4
    const float vv[4] = {v.x, v.y, v.z, v.w};
    H2U h[4], l[4];
    #pragma unroll
    for (int z = 0; z < 4; ++z) {
      h[z].h = (_Float16)vv[z];
      l[z].h = (_Float16)(vv[z] - (float)h[z].h);
    }
    const int off = ((g * 64 + m) * 8 + j0) ^ ((g & 7) << 3);
    uint2 hp, lp;
    hp.x = h[0].u | ((unsigned)h[1].u << 16); hp.y = h[2].u | ((unsigned)h[3].u << 16);
    lp.x = l[0].u | ((unsigned)l[1].u << 16); lp.y = l[2].u | ((unsigned)l[3].u << 16);
    *(uint2*)(Ah + off) = hp;
    *(uint2*)(Al + off) = lp;
  }
  __syncthreads();   // A visible; NO barrier in main loop after this

  // ---- x2 per point (thread tid<64 owns m=tid); A persists in LDS ----
  float x2m = 0.f;
  if (tid < MT) {
    #pragma unroll
    for (int g = 0; g < 16; ++g) {
      const int off = ((g * 64 + tid) * 8) ^ ((g & 7) << 3);
      const f16x8 hv = *(const f16x8*)(Ah + off);
      const f16x8 lv = *(const f16x8*)(Al + off);
      #pragma unroll
      for (int e = 0; e < 8; ++e) {
        const float xv = (float)hv[e] + (float)lv[e];
        x2m += xv * xv;
      }
    }
  }

  // B fragment addresses (L2-resident, fragment-major); loads are TRANSIENT,
  // one chunk in flight (kc loop is unroll-1 -> no cross-chunk hoisting)
  auto bhPtr = [&](int cc, int t) {
    return (const f16x8*)(Bh_g +
        ((size_t)(cc * 4 + q) * 128 + wc * 64 + t * 16 + ln) * 8);
  };
  auto blPtr = [&](int cc, int t) {
    return (const f16x8*)(Bl_g +
        ((size_t)(cc * 4 + q) * 128 + wc * 64 + t * 16 + ln) * 8);
  };

  float bestV[8]; int bestI[8];
  #pragma unroll
  for (int b = 0; b < 8; ++b) { bestV[b] = 3.4e38f; bestI[b] = 0; }

  #pragma unroll 1
  for (int ct = 0; ct < 8; ++ct) {
    f32x4 acc[2][4];
    #pragma unroll
    for (int mt = 0; mt < 2; ++mt)
      #pragma unroll
      for (int nt = 0; nt < 4; ++nt)
        acc[mt][nt] = (f32x4){0.f, 0.f, 0.f, 0.f};

    // c2 for this ct tile, direct from L2
    float c2v[4];
    #pragma unroll
    for (int nt = 0; nt < 4; ++nt)
      c2v[nt] = c2g[ct * 128 + wc * 64 + nt * 16 + ln];

    #pragma unroll 1
    for (int kc = 0; kc < 4; ++kc) {
      const int cc = ct * 4 + kc;              // chunk id

      // transient B fragments from L2: issue first, consume after ds_reads
      f16x8 bh[4], bl[4];
      #pragma unroll
      for (int t = 0; t < 4; ++t) { bh[t] = *bhPtr(cc, t); bl[t] = *blPtr(cc, t); }

      f16x8 ah[2], al[2];
      #pragma unroll
      for (int t = 0; t < 2; ++t) {
        const int gg = kc * 4 + q;
        const int row = wr * 32 + t * 16 + ln;
        const int moff = ((gg * 64 + row) * 8) ^ ((gg & 7) << 3);
        ah[t] = *(const f16x8*)(Ah + moff);
        al[t] = *(const f16x8*)(Al + moff);
      }

      // 3-pass split-f16: 24 MFMA per chunk
      __builtin_amdgcn_s_setprio(1);
      #pragma unroll
      for (int mt = 0; mt < 2; ++mt)
        #pragma unroll
        for (int nt = 0; nt < 4; ++nt)
          acc[mt][nt] = __builtin_amdgcn_mfma_f32_16x16x32_f16(ah[mt], bh[nt], acc[mt][nt], 0, 0, 0);
      #pragma unroll
      for (int mt = 0; mt < 2; ++mt)
        #pragma unroll
        for (int nt = 0; nt < 4; ++nt)
          acc[mt][nt] = __builtin_amdgcn_mfma_f32_16x16x32_f16(al[mt], bh[nt], acc[mt][nt], 0, 0, 0);
      #pragma unroll
      for (int mt = 0; mt < 2; ++mt)
        #pragma unroll
        for (int nt = 0; nt < 4; ++nt)
          acc[mt][nt] = __builtin_amdgcn_mfma_f32_16x16x32_f16(ah[mt], bl[nt], acc[mt][nt], 0, 0, 0);
      __builtin_amdgcn_s_setprio(0);
    }

    // epilogue: s = c2 - 2*dot; running min (n strictly increasing per lane)
    #pragma unroll
    for (int nt = 0; nt < 4; ++nt) {
      const int n = ct * 128 + wc * 64 + nt * 16 + ln;
      #pragma unroll
      for (int mt = 0; mt < 2; ++mt)
        #pragma unroll
        for (int r = 0; r < 4; ++r) {
          const float s = __builtin_fmaf(-2.f, acc[mt][nt][r], c2v[nt]);
          const int b = mt * 4 + r;
          if (s < bestV[b]) { bestV[b] = s; bestI[b] = n; }
        }
    }
  }

  // ---- reduce across the 16 lanes (ln) sharing the same m rows ----
  #pragma unroll
  for (int b = 0; b < 8; ++b) {
    float v = bestV[b]; int idx = bestI[b];
    #pragma unroll
    for (int off = 1; off < 16; off <<= 1) {
      const float ov = __shfl_xor(v, off, 64);
      const int   oi = __shfl_xor(idx, off, 64);
      if (ov < v || (ov == v && oi < idx)) { v = ov; idx = oi; }
    }
    bestV[b] = v; bestI[b] = idx;
  }

  float* redV = (float*)(smem + 16384);  // 512 B (128 floats), disjoint from A
  int*   redI = (int*)(smem + 16640);    // 512 B
  if (ln == 0) {
    #pragma unroll
    for (int b = 0; b < 8; ++b) {
      const int ml = wr * 32 + (b >> 2) * 16 + q * 4 + (b & 3);
      redV[ml * 2 + wc] = bestV[b];
      redI[ml * 2 + wc] = bestI[b];
    }
  }
  __syncthreads();   // reduce writes visible
  if (tid < MT) {
    float v = redV[tid * 2]; int idx = redI[tid * 2];
    const float v1 = redV[tid * 2 + 1]; const int i1 = redI[tid * 2 + 1];
    if (v1 < v || (v1 == v && i1 < idx)) { v = v1; idx = i1; }
    float cost = x2m + v;
    if (cost < 0.f) cost = 0.f;          // clamp like reference
    out_cost[m0 + tid] = cost;
    out_idx[m0 + tid]  = (float)idx;
  }
}

extern "C" void kernel_launch(void* const* d_in, const int* in_sizes, int n_in,
                              void* d_out, int out_size, void* d_ws, size_t ws_size,
                              hipStream_t stream) {
  const float* x       = (const float*)d_in[0];
  const float* centers = (const float*)d_in[1];
  u16*   Bh = (u16*)d_ws;                    // 256 KB
  u16*   Bl = Bh + (size_t)K * D;            // 256 KB
  float* c2 = (float*)(Bl + (size_t)K * D);  // 4 KB
  float* out_cost = (float*)d_out;
  float* out_idx  = out_cost + N;

  prep_centers<<<K / 4, 256, 0, stream>>>(centers, Bh, Bl, c2);
  kmeans_mfma<<<N / MT, 256, 0, stream>>>(x, Bh, Bl, c2, out_cost, out_idx);
}

// Round 7
// 187.241 us; speedup vs baseline: 1.7710x; 1.0275x over previous
//
#include <hip/hip_runtime.h>

// KMeans assignment: costs[i] = min_k ||x_i-c_k||^2, indices[i] = argmin_k.
// argmin over k of (c2[k] - 2*dot(x,c_k)); x2 additive, added at the end.
// Cross term via split-f16 3-pass MFMA (xh.ch + xl.ch + xh.cl), err ~1e-6.
// R12 = R11 (MT=64 barrier-free, no-spill, VGPR 68) + two surgical fixes:
//  - R11 stalled per-chunk: B loads issued and consumed in the SAME chunk
//    -> each wave's MFMA duty ~116cyc/(L2 latency 200-300 + compute) ~ 40%
//    == measured MfmaUtil 40-43. Fix: prefetch ONLY bh one chunk ahead
//    (+16 regs, bhc/bhn named rotate; kc stays unroll-1 so nothing else
//    hoists -- R10's blowup was full-unroll hoisting 4 chunks). bl stays
//    transient: consumed at pass 3, ~160cyc after issue, self-hiding.
//  - VALUBusy 44% ~ half address math (unroll-1 recomputed 8 64-bit
//    addresses/chunk). Fix: single unsigned byte-offset vb += 8192/chunk;
//    loads are SGPR-base + vb + literal -> ~1 VALU/chunk.
//  - __launch_bounds__(256,3): cap VGPR ~168 (est live ~135) -> 3 waves/
//    SIMD, 3 blocks/CU (LDS 3x33KB fits 160KB).
// Kept: A LDS XOR-swizzle (conflicts 3.68M->8.2K, R6-proven), setprio.
// Known-bad: full B dbuf in regs at fat tiles (R6/R10 spill); packed-key
// argmin (R7 near-tie flips); mid-chunk barrier (R8 -13%); sched_barrier
// pins (R9 spill).
// N=131072, D=128, K=1024.  d_out = [costs (N f32), indices-as-f32 (N)].

typedef _Float16 f16x8 __attribute__((ext_vector_type(8)));
typedef float    f32x4 __attribute__((ext_vector_type(4)));
typedef unsigned short u16;

constexpr int N = 131072, D = 128, K = 1024;
constexpr int MT = 64;    // points per block

union H2U { _Float16 h; unsigned short u; };

// ---- prep: centers -> hi/lo f16 in fragment-major tiled layout + exact c2 ----
// ushort idx: (((cb*4 + kc)*4 + q)*128 + c%128)*8 + j, k = kc*32 + q*8 + j
__global__ void prep_centers(const float* __restrict__ centers,
                             u16* __restrict__ Bh, u16* __restrict__ Bl,
                             float* __restrict__ c2) {
  const int wave = threadIdx.x >> 6, lane = threadIdx.x & 63;
  const int c = blockIdx.x * 4 + wave;          // one wave per center
  const float2 v = ((const float2*)(centers + (size_t)c * D))[lane];
  float s = v.x * v.x + v.y * v.y;
  #pragma unroll
  for (int off = 32; off; off >>= 1) s += __shfl_xor(s, off, 64);
  if (lane == 0) c2[c] = s;

  H2U h0, h1, l0, l1;
  h0.h = (_Float16)v.x;  l0.h = (_Float16)(v.x - (float)h0.h);
  h1.h = (_Float16)v.y;  l1.h = (_Float16)(v.y - (float)h1.h);
  const int cb = c >> 7, cm = c & 127;
  const int kc = lane >> 4, q = (lane >> 2) & 3, j0 = (lane & 3) * 2;
  const size_t off = (((size_t)(cb * 4 + kc) * 4 + q) * 128 + cm) * 8 + j0;
  *(unsigned*)(Bh + off) = (unsigned)h0.u | ((unsigned)h1.u << 16);
  *(unsigned*)(Bl + off) = (unsigned)l0.u | ((unsigned)l1.u << 16);
}

// ---- main: 64 pts x 1024 centers per block; wave tile 32x64 (2x2 waves) ----
__global__ __launch_bounds__(256, 3) void kmeans_mfma(
    const float* __restrict__ x,
    const u16* __restrict__ Bh_g, const u16* __restrict__ Bl_g,
    const float* __restrict__ c2g,
    float* __restrict__ out_cost, float* __restrict__ out_idx)
{
  // 33 KB: Ah [0,8192) u16, Al [8192,16384), red [16384,16896)
  __shared__ __align__(16) u16 smem[16896];
  u16* Ah = smem;            // [g16][m64][j8] swizzled  16 KB
  u16* Al = smem + 8192;     //                          16 KB

  const int tid = threadIdx.x;
  const int wave = tid >> 6, lane = tid & 63;
  const int wr = wave >> 1, wc = wave & 1;    // wave row/col in 2x2
  const int q = lane >> 4, ln = lane & 15;
  const int m0 = blockIdx.x * MT;

  // ---- stage A tile: fp32 -> (hi,lo) f16, XOR-swizzled tiled layout ----
  #pragma unroll
  for (int i = 0; i < 8; ++i) {
    const int flat = i * 256 + tid;            // 2048 float4s = 64x128 floats
    const int m = flat >> 5, c4 = flat & 31, k0 = c4 * 4;
    const float4 v = *(const float4*)(x + (size_t)(m0 + m) * D + k0);
    const int g = k0 >> 3;                     // k-group in [0,16)
    const int j0 = k0 & 7;                     // 0 or 4
    const float vv[4] = {v.x, v.y, v.z, v.w};
    H2U h[4], l[4];
    #pragma unroll
    for (int z = 0; z < 4; ++z) {
      h[z].h = (_Float16)vv[z];
      l[z].h = (_Float16)(vv[z] - (float)h[z].h);
    }
    const int off = ((g * 64 + m) * 8 + j0) ^ ((g & 7) << 3);
    uint2 hp, lp;
    hp.x = h[0].u | ((unsigned)h[1].u << 16); hp.y = h[2].u | ((unsigned)h[3].u << 16);
    lp.x = l[0].u | ((unsigned)l[1].u << 16); lp.y = l[2].u | ((unsigned)l[3].u << 16);
    *(uint2*)(Ah + off) = hp;
    *(uint2*)(Al + off) = lp;
  }
  __syncthreads();   // A visible; NO barrier in main loop after this

  // ---- x2 per point (thread tid<64 owns m=tid); A persists in LDS ----
  float x2m = 0.f;
  if (tid < MT) {
    #pragma unroll
    for (int g = 0; g < 16; ++g) {
      const int off = ((g * 64 + tid) * 8) ^ ((g & 7) << 3);
      const f16x8 hv = *(const f16x8*)(Ah + off);
      const f16x8 lv = *(const f16x8*)(Al + off);
      #pragma unroll
      for (int e = 0; e < 8; ++e) {
        const float xv = (float)hv[e] + (float)lv[e];
        x2m += xv * xv;
      }
    }
  }

  // B addressing: byte offset, element ((cc*4+q)*128 + wc*64 + t*16 + ln)*8
  //   = cc*8192 + q*2048 + (wc*64+ln)*16 + t*256 bytes.
  // One running vb (+8192/chunk); t*256 folds into the load's literal offset.
  const char* BhB = (const char*)Bh_g;
  const char* BlB = (const char*)Bl_g;
  unsigned vb = (unsigned)(q * 2048 + (wc * 64 + ln) * 16);

  float bestV[8]; int bestI[8];
  #pragma unroll
  for (int b = 0; b < 8; ++b) { bestV[b] = 3.4e38f; bestI[b] = 0; }

  // prologue: bh for chunk 0 in flight
  f16x8 bhc[4];
  #pragma unroll
  for (int t = 0; t < 4; ++t)
    bhc[t] = *(const f16x8*)(BhB + vb + t * 256);

  #pragma unroll 1
  for (int ct = 0; ct < 8; ++ct) {
    f32x4 acc[2][4];
    #pragma unroll
    for (int mt = 0; mt < 2; ++mt)
      #pragma unroll
      for (int nt = 0; nt < 4; ++nt)
        acc[mt][nt] = (f32x4){0.f, 0.f, 0.f, 0.f};

    // c2 for this ct tile (L2); consumed 4 chunks later -> latency hidden
    float c2v[4];
    #pragma unroll
    for (int nt = 0; nt < 4; ++nt)
      c2v[nt] = c2g[ct * 128 + wc * 64 + nt * 16 + ln];

    #pragma unroll 1
    for (int kc = 0; kc < 4; ++kc) {
      // current-chunk bl (consumed at pass 3 -> self-hiding) and
      // next-chunk bh (consumed next iteration). cc=31's bhn reads past
      // Bh into Bl (same workspace, harmless, never consumed).
      f16x8 bl[4], bhn[4];
      #pragma unroll
      for (int t = 0; t < 4; ++t)
        bl[t] = *(const f16x8*)(BlB + vb + t * 256);
      #pragma unroll
      for (int t = 0; t < 4; ++t)
        bhn[t] = *(const f16x8*)(BhB + (vb + 8192) + t * 256);

      f16x8 ah[2], al[2];
      #pragma unroll
      for (int t = 0; t < 2; ++t) {
        const int gg = kc * 4 + q;
        const int row = wr * 32 + t * 16 + ln;
        const int moff = ((gg * 64 + row) * 8) ^ ((gg & 7) << 3);
        ah[t] = *(const f16x8*)(Ah + moff);
        al[t] = *(const f16x8*)(Al + moff);
      }

      // 3-pass split-f16: 24 MFMA per chunk (bhc already resident)
      __builtin_amdgcn_s_setprio(1);
      #pragma unroll
      for (int mt = 0; mt < 2; ++mt)
        #pragma unroll
        for (int nt = 0; nt < 4; ++nt)
          acc[mt][nt] = __builtin_amdgcn_mfma_f32_16x16x32_f16(ah[mt], bhc[nt], acc[mt][nt], 0, 0, 0);
      #pragma unroll
      for (int mt = 0; mt < 2; ++mt)
        #pragma unroll
        for (int nt = 0; nt < 4; ++nt)
          acc[mt][nt] = __builtin_amdgcn_mfma_f32_16x16x32_f16(al[mt], bhc[nt], acc[mt][nt], 0, 0, 0);
      #pragma unroll
      for (int mt = 0; mt < 2; ++mt)
        #pragma unroll
        for (int nt = 0; nt < 4; ++nt)
          acc[mt][nt] = __builtin_amdgcn_mfma_f32_16x16x32_f16(ah[mt], bl[nt], acc[mt][nt], 0, 0, 0);
      __builtin_amdgcn_s_setprio(0);

      #pragma unroll
      for (int t = 0; t < 4; ++t) bhc[t] = bhn[t];   // rotate prefetch
      vb += 8192;
    }

    // epilogue: s = c2 - 2*dot; running min (n strictly increasing per lane)
    #pragma unroll
    for (int nt = 0; nt < 4; ++nt) {
      const int n = ct * 128 + wc * 64 + nt * 16 + ln;
      #pragma unroll
      for (int mt = 0; mt < 2; ++mt)
        #pragma unroll
        for (int r = 0; r < 4; ++r) {
          const float s = __builtin_fmaf(-2.f, acc[mt][nt][r], c2v[nt]);
          const int b = mt * 4 + r;
          if (s < bestV[b]) { bestV[b] = s; bestI[b] = n; }
        }
    }
  }

  // ---- reduce across the 16 lanes (ln) sharing the same m rows ----
  #pragma unroll
  for (int b = 0; b < 8; ++b) {
    float v = bestV[b]; int idx = bestI[b];
    #pragma unroll
    for (int off = 1; off < 16; off <<= 1) {
      const float ov = __shfl_xor(v, off, 64);
      const int   oi = __shfl_xor(idx, off, 64);
      if (ov < v || (ov == v && oi < idx)) { v = ov; idx = oi; }
    }
    bestV[b] = v; bestI[b] = idx;
  }

  float* redV = (float*)(smem + 16384);  // 512 B, disjoint from A
  int*   redI = (int*)(smem + 16640);    // 512 B
  if (ln == 0) {
    #pragma unroll
    for (int b = 0; b < 8; ++b) {
      const int ml = wr * 32 + (b >> 2) * 16 + q * 4 + (b & 3);
      redV[ml * 2 + wc] = bestV[b];
      redI[ml * 2 + wc] = bestI[b];
    }
  }
  __syncthreads();   // reduce writes visible
  if (tid < MT) {
    float v = redV[tid * 2]; int idx = redI[tid * 2];
    const float v1 = redV[tid * 2 + 1]; const int i1 = redI[tid * 2 + 1];
    if (v1 < v || (v1 == v && i1 < idx)) { v = v1; idx = i1; }
    float cost = x2m + v;
    if (cost < 0.f) cost = 0.f;          // clamp like reference
    out_cost[m0 + tid] = cost;
    out_idx[m0 + tid]  = (float)idx;
  }
}

extern "C" void kernel_launch(void* const* d_in, const int* in_sizes, int n_in,
                              void* d_out, int out_size, void* d_ws, size_t ws_size,
                              hipStream_t stream) {
  const float* x       = (const float*)d_in[0];
  const float* centers = (const float*)d_in[1];
  u16*   Bh = (u16*)d_ws;                    // 256 KB
  u16*   Bl = Bh + (size_t)K * D;            // 256 KB
  float* c2 = (float*)(Bl + (size_t)K * D);  // 4 KB
  float* out_cost = (float*)d_out;
  float* out_idx  = out_cost + N;

  prep_centers<<<K / 4, 256, 0, stream>>>(centers, Bh, Bl, c2);
  kmeans_mfma<<<N / MT, 256, 0, stream>>>(x, Bh, Bl, c2, out_cost, out_idx);
}

// Round 8
// 186.313 us; speedup vs baseline: 1.7798x; 1.0050x over previous
//
#include <hip/hip_runtime.h>

// KMeans assignment: costs[i] = min_k ||x_i-c_k||^2, indices[i] = argmin_k.
// argmin over k of (c2[k] - 2*dot(x,c_k)); x2 additive, added at the end.
// Cross term via split-f16 3-pass MFMA (xh.ch + xl.ch + xh.cl), err ~1e-6.
// R13 = R12 with __launch_bounds__(256,4): occupancy was THE limiter.
//   Evidence: MfmaUtil 43% x 113us == 49us == static MFMA floor (1.03e11
//   FLOP @ 2075 TF) -> matrix pipe idles 57%; occupancy 28% = 2.3 blocks/
//   CU = 2.3 waves/SIMD. Each wave alternates {8 L2 loads + 4 ds_read +
//   VALU} <-> {24 MFMA ~ 470cyc}; with ~2 co-resident waves/SIMD there is
//   rarely another wave in its MFMA phase to cover the gap (m114 pipes CAN
//   co-issue across waves -- we lack waves, not pipes). LDS 33KB x 4 =
//   132 <= 160KB and VGPR 68 <= 128 both permit 4 blocks/CU; only the
//   (256,3) bound blocked it. One-line change -> clean A/B vs R12.
// Kept from R12: MT=64 wave-tile 32x64 barrier-free loop; bh one-chunk
//   register prefetch (bhc/bhn rotate, kc unroll-1 bounds hoisting); bl
//   transient (consumed pass 3, self-hiding); byte-offset vb addressing;
//   A LDS XOR-swizzle (conflicts 3.68M->8.2K); setprio on MFMA cluster.
// Known-bad: full B dbuf in regs at fat tiles (R6/R10 spill); packed-key
// argmin (R7 near-tie flips); mid-chunk barrier (R8 -13%); sched_barrier
// pins (R9 spill).
// N=131072, D=128, K=1024.  d_out = [costs (N f32), indices-as-f32 (N)].

typedef _Float16 f16x8 __attribute__((ext_vector_type(8)));
typedef float    f32x4 __attribute__((ext_vector_type(4)));
typedef unsigned short u16;

constexpr int N = 131072, D = 128, K = 1024;
constexpr int MT = 64;    // points per block

union H2U { _Float16 h; unsigned short u; };

// ---- prep: centers -> hi/lo f16 in fragment-major tiled layout + exact c2 ----
// ushort idx: (((cb*4 + kc)*4 + q)*128 + c%128)*8 + j, k = kc*32 + q*8 + j
__global__ void prep_centers(const float* __restrict__ centers,
                             u16* __restrict__ Bh, u16* __restrict__ Bl,
                             float* __restrict__ c2) {
  const int wave = threadIdx.x >> 6, lane = threadIdx.x & 63;
  const int c = blockIdx.x * 4 + wave;          // one wave per center
  const float2 v = ((const float2*)(centers + (size_t)c * D))[lane];
  float s = v.x * v.x + v.y * v.y;
  #pragma unroll
  for (int off = 32; off; off >>= 1) s += __shfl_xor(s, off, 64);
  if (lane == 0) c2[c] = s;

  H2U h0, h1, l0, l1;
  h0.h = (_Float16)v.x;  l0.h = (_Float16)(v.x - (float)h0.h);
  h1.h = (_Float16)v.y;  l1.h = (_Float16)(v.y - (float)h1.h);
  const int cb = c >> 7, cm = c & 127;
  const int kc = lane >> 4, q = (lane >> 2) & 3, j0 = (lane & 3) * 2;
  const size_t off = (((size_t)(cb * 4 + kc) * 4 + q) * 128 + cm) * 8 + j0;
  *(unsigned*)(Bh + off) = (unsigned)h0.u | ((unsigned)h1.u << 16);
  *(unsigned*)(Bl + off) = (unsigned)l0.u | ((unsigned)l1.u << 16);
}

// ---- main: 64 pts x 1024 centers per block; wave tile 32x64 (2x2 waves) ----
__global__ __launch_bounds__(256, 4) void kmeans_mfma(
    const float* __restrict__ x,
    const u16* __restrict__ Bh_g, const u16* __restrict__ Bl_g,
    const float* __restrict__ c2g,
    float* __restrict__ out_cost, float* __restrict__ out_idx)
{
  // 33 KB: Ah [0,8192) u16, Al [8192,16384), red [16384,16896)
  __shared__ __align__(16) u16 smem[16896];
  u16* Ah = smem;            // [g16][m64][j8] swizzled  16 KB
  u16* Al = smem + 8192;     //                          16 KB

  const int tid = threadIdx.x;
  const int wave = tid >> 6, lane = tid & 63;
  const int wr = wave >> 1, wc = wave & 1;    // wave row/col in 2x2
  const int q = lane >> 4, ln = lane & 15;
  const int m0 = blockIdx.x * MT;

  // ---- stage A tile: fp32 -> (hi,lo) f16, XOR-swizzled tiled layout ----
  #pragma unroll
  for (int i = 0; i < 8; ++i) {
    const int flat = i * 256 + tid;            // 2048 float4s = 64x128 floats
    const int m = flat >> 5, c4 = flat & 31, k0 = c4 * 4;
    const float4 v = *(const float4*)(x + (size_t)(m0 + m) * D + k0);
    const int g = k0 >> 3;                     // k-group in [0,16)
    const int j0 = k0 & 7;                     // 0 or 4
    const float vv[4] = {v.x, v.y, v.z, v.w};
    H2U h[4], l[4];
    #pragma unroll
    for (int z = 0; z < 4; ++z) {
      h[z].h = (_Float16)vv[z];
      l[z].h = (_Float16)(vv[z] - (float)h[z].h);
    }
    const int off = ((g * 64 + m) * 8 + j0) ^ ((g & 7) << 3);
    uint2 hp, lp;
    hp.x = h[0].u | ((unsigned)h[1].u << 16); hp.y = h[2].u | ((unsigned)h[3].u << 16);
    lp.x = l[0].u | ((unsigned)l[1].u << 16); lp.y = l[2].u | ((unsigned)l[3].u << 16);
    *(uint2*)(Ah + off) = hp;
    *(uint2*)(Al + off) = lp;
  }
  __syncthreads();   // A visible; NO barrier in main loop after this

  // ---- x2 per point (thread tid<64 owns m=tid); A persists in LDS ----
  float x2m = 0.f;
  if (tid < MT) {
    #pragma unroll
    for (int g = 0; g < 16; ++g) {
      const int off = ((g * 64 + tid) * 8) ^ ((g & 7) << 3);
      const f16x8 hv = *(const f16x8*)(Ah + off);
      const f16x8 lv = *(const f16x8*)(Al + off);
      #pragma unroll
      for (int e = 0; e < 8; ++e) {
        const float xv = (float)hv[e] + (float)lv[e];
        x2m += xv * xv;
      }
    }
  }

  // B addressing: byte offset, element ((cc*4+q)*128 + wc*64 + t*16 + ln)*8
  //   = cc*8192 + q*2048 + (wc*64+ln)*16 + t*256 bytes.
  // One running vb (+8192/chunk); t*256 folds into the load's literal offset.
  const char* BhB = (const char*)Bh_g;
  const char* BlB = (const char*)Bl_g;
  unsigned vb = (unsigned)(q * 2048 + (wc * 64 + ln) * 16);

  float bestV[8]; int bestI[8];
  #pragma unroll
  for (int b = 0; b < 8; ++b) { bestV[b] = 3.4e38f; bestI[b] = 0; }

  // prologue: bh for chunk 0 in flight
  f16x8 bhc[4];
  #pragma unroll
  for (int t = 0; t < 4; ++t)
    bhc[t] = *(const f16x8*)(BhB + vb + t * 256);

  #pragma unroll 1
  for (int ct = 0; ct < 8; ++ct) {
    f32x4 acc[2][4];
    #pragma unroll
    for (int mt = 0; mt < 2; ++mt)
      #pragma unroll
      for (int nt = 0; nt < 4; ++nt)
        acc[mt][nt] = (f32x4){0.f, 0.f, 0.f, 0.f};

    // c2 for this ct tile (L2); consumed 4 chunks later -> latency hidden
    float c2v[4];
    #pragma unroll
    for (int nt = 0; nt < 4; ++nt)
      c2v[nt] = c2g[ct * 128 + wc * 64 + nt * 16 + ln];

    #pragma unroll 1
    for (int kc = 0; kc < 4; ++kc) {
      // current-chunk bl (consumed at pass 3 -> self-hiding) and
      // next-chunk bh (consumed next iteration). cc=31's bhn reads past
      // Bh into Bl (same workspace, harmless, never consumed).
      f16x8 bl[4], bhn[4];
      #pragma unroll
      for (int t = 0; t < 4; ++t)
        bl[t] = *(const f16x8*)(BlB + vb + t * 256);
      #pragma unroll
      for (int t = 0; t < 4; ++t)
        bhn[t] = *(const f16x8*)(BhB + (vb + 8192) + t * 256);

      f16x8 ah[2], al[2];
      #pragma unroll
      for (int t = 0; t < 2; ++t) {
        const int gg = kc * 4 + q;
        const int row = wr * 32 + t * 16 + ln;
        const int moff = ((gg * 64 + row) * 8) ^ ((gg & 7) << 3);
        ah[t] = *(const f16x8*)(Ah + moff);
        al[t] = *(const f16x8*)(Al + moff);
      }

      // 3-pass split-f16: 24 MFMA per chunk (bhc already resident)
      __builtin_amdgcn_s_setprio(1);
      #pragma unroll
      for (int mt = 0; mt < 2; ++mt)
        #pragma unroll
        for (int nt = 0; nt < 4; ++nt)
          acc[mt][nt] = __builtin_amdgcn_mfma_f32_16x16x32_f16(ah[mt], bhc[nt], acc[mt][nt], 0, 0, 0);
      #pragma unroll
      for (int mt = 0; mt < 2; ++mt)
        #pragma unroll
        for (int nt = 0; nt < 4; ++nt)
          acc[mt][nt] = __builtin_amdgcn_mfma_f32_16x16x32_f16(al[mt], bhc[nt], acc[mt][nt], 0, 0, 0);
      #pragma unroll
      for (int mt = 0; mt < 2; ++mt)
        #pragma unroll
        for (int nt = 0; nt < 4; ++nt)
          acc[mt][nt] = __builtin_amdgcn_mfma_f32_16x16x32_f16(ah[mt], bl[nt], acc[mt][nt], 0, 0, 0);
      __builtin_amdgcn_s_setprio(0);

      #pragma unroll
      for (int t = 0; t < 4; ++t) bhc[t] = bhn[t];   // rotate prefetch
      vb += 8192;
    }

    // epilogue: s = c2 - 2*dot; running min (n strictly increasing per lane)
    #pragma unroll
    for (int nt = 0; nt < 4; ++nt) {
      const int n = ct * 128 + wc * 64 + nt * 16 + ln;
      #pragma unroll
      for (int mt = 0; mt < 2; ++mt)
        #pragma unroll
        for (int r = 0; r < 4; ++r) {
          const float s = __builtin_fmaf(-2.f, acc[mt][nt][r], c2v[nt]);
          const int b = mt * 4 + r;
          if (s < bestV[b]) { bestV[b] = s; bestI[b] = n; }
        }
    }
  }

  // ---- reduce across the 16 lanes (ln) sharing the same m rows ----
  #pragma unroll
  for (int b = 0; b < 8; ++b) {
    float v = bestV[b]; int idx = bestI[b];
    #pragma unroll
    for (int off = 1; off < 16; off <<= 1) {
      const float ov = __shfl_xor(v, off, 64);
      const int   oi = __shfl_xor(idx, off, 64);
      if (ov < v || (ov == v && oi < idx)) { v = ov; idx = oi; }
    }
    bestV[b] = v; bestI[b] = idx;
  }

  float* redV = (float*)(smem + 16384);  // 512 B, disjoint from A
  int*   redI = (int*)(smem + 16640);    // 512 B
  if (ln == 0) {
    #pragma unroll
    for (int b = 0; b < 8; ++b) {
      const int ml = wr * 32 + (b >> 2) * 16 + q * 4 + (b & 3);
      redV[ml * 2 + wc] = bestV[b];
      redI[ml * 2 + wc] = bestI[b];
    }
  }
  __syncthreads();   // reduce writes visible
  if (tid < MT) {
    float v = redV[tid * 2]; int idx = redI[tid * 2];
    const float v1 = redV[tid * 2 + 1]; const int i1 = redI[tid * 2 + 1];
    if (v1 < v || (v1 == v && i1 < idx)) { v = v1; idx = i1; }
    float cost = x2m + v;
    if (cost < 0.f) cost = 0.f;          // clamp like reference
    out_cost[m0 + tid] = cost;
    out_idx[m0 + tid]  = (float)idx;
  }
}

extern "C" void kernel_launch(void* const* d_in, const int* in_sizes, int n_in,
                              void* d_out, int out_size, void* d_ws, size_t ws_size,
                              hipStream_t stream) {
  const float* x       = (const float*)d_in[0];
  const float* centers = (const float*)d_in[1];
  u16*   Bh = (u16*)d_ws;                    // 256 KB
  u16*   Bl = Bh + (size_t)K * D;            // 256 KB
  float* c2 = (float*)(Bl + (size_t)K * D);  // 4 KB
  float* out_cost = (float*)d_out;
  float* out_idx  = out_cost + N;

  prep_centers<<<K / 4, 256, 0, stream>>>(centers, Bh, Bl, c2);
  kmeans_mfma<<<N / MT, 256, 0, stream>>>(x, Bh, Bl, c2, out_cost, out_idx);
}